// Round 9
// baseline (270.255 us; speedup 1.0000x reference)
//
#include <hip/hip_runtime.h>

#define Bn 4096
#define En 1024
#define On 16
#define Hn 1024
#define OHn (On * Hn)

#define BM 32
#define BN 128
#define BK 64
#define MAXT 160  // max tiles: sum ceil(cnt/32) <= 128 + 16 = 144 <= 160

using floatx4 = __attribute__((ext_vector_type(4))) float;
using float4v = __attribute__((ext_vector_type(4))) float;
using bf16x8  = __attribute__((ext_vector_type(8))) __bf16;
using short8v = __attribute__((ext_vector_type(8))) short;
using short4v = __attribute__((ext_vector_type(4))) short;

__device__ inline unsigned short f2bf(float f) {
    unsigned u = __builtin_bit_cast(unsigned, f);
    u += 0x7fffu + ((u >> 16) & 1u);   // RNE to bf16 (inputs finite)
    return (unsigned short)(u >> 16);
}

// LDS column swizzle: XOR bits[1:0] of the 16B-cell index with bits[4:3].
// Bijective; spreads k-octet-major B writes and fragment reads across banks
// with compile-time vector indices only (rule #20).
__device__ __forceinline__ int swz(int col) { return col ^ ((col >> 3) & 3); }

// ---------------- bucket examples by op + build compact tile list ----------------
__global__ void bucket_kernel(const int* __restrict__ op_idx,
                              int* __restrict__ sorted_idx,
                              int* __restrict__ offsets,
                              int* __restrict__ tile_o,
                              int* __restrict__ tile_m) {
    __shared__ int cnt[On], cur[On], off[On + 1];
    int tid = threadIdx.x;
    if (tid < On) { cnt[tid] = 0; cur[tid] = 0; }
    __syncthreads();
    for (int i = tid; i < Bn; i += blockDim.x) atomicAdd(&cnt[op_idx[i]], 1);
    __syncthreads();
    if (tid == 0) {
        int s = 0;
        for (int o = 0; o < On; ++o) { off[o] = s; s += cnt[o]; }
        off[On] = s;
        int nt = 0;
        for (int o = 0; o < On; ++o)
            for (int m0 = 0; m0 < cnt[o]; m0 += BM) { tile_o[nt] = o; tile_m[nt] = m0; ++nt; }
        for (; nt < MAXT; ++nt) { tile_o[nt] = -1; tile_m[nt] = 0; }
    }
    __syncthreads();
    for (int i = tid; i < Bn; i += blockDim.x) {
        int o = op_idx[i];
        int p = off[o] + atomicAdd(&cur[o], 1);
        sorted_idx[p] = i;
    }
    if (tid <= On) offsets[tid] = off[tid];
}

// ---------------- pack x: gather rows into sorted order, fp32 -> bf16 ----------------
__global__ __launch_bounds__(256) void pack_x_kernel(const float* __restrict__ x,
                                                     const int* __restrict__ sorted_idx,
                                                     unsigned short* __restrict__ x_s) {
    int p0 = blockIdx.x * 4, t = threadIdx.x;
#pragma unroll
    for (int r = 0; r < 4; ++r) {
        int p = p0 + r;
        int row = sorted_idx[p];
        float4v v = *(const float4v*)(x + (size_t)row * En + t * 4);
        short4v w;
#pragma unroll
        for (int j = 0; j < 4; ++j) w[j] = (short)f2bf(v[j]);
        *(short4v*)&x_s[(size_t)p * En + t * 4] = w;
    }
}

// ================================================================================
// Direct-W GEMM, BM=32 for TLP: 1280 blocks = 5/CU = 20 waves/CU (round-8 was 2.5
// blocks/CU and latency-bound at 16% occupancy). B staged straight from W [K][O][H]
// fp32 (float4 coalesced), reg-transposed to granule layout (compile-time indices),
// LDS bank spread via address swizzle. Single 20KB LDS buffer.
// ================================================================================

// ---------------- layer 1: h1 = relu(x_s @ W1[:,o,:] + b1[o]) ----------------
__global__ __launch_bounds__(256) void gemm1_kernel(
    const unsigned short* __restrict__ x_s, const float* __restrict__ W,
    const float* __restrict__ bias1, const int* __restrict__ offsets,
    const int* __restrict__ tile_o, const int* __restrict__ tile_m,
    unsigned short* __restrict__ h1) {
    int o = tile_o[blockIdx.y];
    if (o < 0) return;
    int m0 = tile_m[blockIdx.y];
    int off = offsets[o];
    int cnt = offsets[o + 1] - off;
    int n0 = blockIdx.x * BN;

    __shared__ __attribute__((aligned(16))) unsigned short As[8][BM][8];  // 4 KB
    __shared__ __attribute__((aligned(16))) unsigned short Bs[8][BN][8];  // 16 KB

    int tid = threadIdx.x;

    // A: thread owns one granule cell (ag, arow)
    int arow = tid & 31, ag = tid >> 5;                // ag 0..7
    int rr = m0 + arow; if (rr >= cnt) rr = cnt - 1;   // clamp: pad rows never stored
    const unsigned short* aBase = x_s + (size_t)(off + rr) * En;

    // B: thread owns k-octet o8 = tid>>5 (rows o8*8..+7), cols c4..c4+3
    int o8 = tid >> 5, c4 = (tid & 31) * 4;
    const float* bBase = W + ((size_t)(o8 * 8) * On + o) * Hn + n0 + c4;

    short8v a_pre;
    float4v b_pre[8];

    auto LOADA = [&](int kt) {
        a_pre = *(const short8v*)(aBase + kt + ag * 8);
    };
    auto LOADB = [&](int kt) {   // 8 x float4; wave covers 2 contiguous 512B rows/instr
        const float* p = bBase + (size_t)kt * OHn;
#pragma unroll
        for (int j = 0; j < 8; ++j) b_pre[j] = *(const float4v*)(p + (size_t)j * OHn);
    };
    auto WRITE = [&]() {
        *(short8v*)&As[ag][arow][0] = a_pre;
#pragma unroll
        for (int cc = 0; cc < 4; ++cc) {            // cc compile-time: b_pre stays in VGPRs
            short8v w;
#pragma unroll
            for (int j = 0; j < 8; ++j) w[j] = (short)f2bf(b_pre[j][cc]);
            *(short8v*)&Bs[o8][swz(c4 + cc)][0] = w;
        }
    };

    floatx4 acc[4] = {};
    int lane = tid & 63, wave = tid >> 6;
    int wm = (wave >> 1) * 16, wn = (wave & 1) * 64;
    int l15 = lane & 15, kg = lane >> 4;

    auto COMPUTE = [&]() {
#pragma unroll
        for (int ks = 0; ks < 2; ++ks) {
            int g = ks * 4 + kg;
            bf16x8 af = *(const bf16x8*)&As[g][wm + l15][0];
            bf16x8 bfr[4];
#pragma unroll
            for (int nt = 0; nt < 4; ++nt) bfr[nt] = *(const bf16x8*)&Bs[g][swz(wn + nt * 16 + l15)][0];
#pragma unroll
            for (int nt = 0; nt < 4; ++nt)
                acc[nt] = __builtin_amdgcn_mfma_f32_16x16x32_bf16(af, bfr[nt], acc[nt], 0, 0, 0);
        }
    };

    LOADA(0); LOADB(0);
    for (int kt = 0; kt < En; kt += BK) {
        WRITE();                         // cvt + LDS store of current tile
        __syncthreads();                 // LDS visible
        int ktn = kt + BK;
        if (ktn < En) { LOADA(ktn); LOADB(ktn); }   // reg prefetch overlaps MFMA
        COMPUTE();
        __syncthreads();                 // all waves done reading before next WRITE
    }

    // epilogue: bias + relu -> h1 (bf16, sorted order)
    int r4 = (lane >> 4) * 4;
#pragma unroll
    for (int nt = 0; nt < 4; ++nt) {
        int col = n0 + wn + nt * 16 + l15;
        float bv = bias1[o * Hn + col];
#pragma unroll
        for (int r = 0; r < 4; ++r) {
            int row = m0 + wm + r4 + r;
            if (row < cnt) {
                float v = acc[nt][r] + bv;
                v = v > 0.f ? v : 0.f;
                h1[(size_t)(off + row) * Hn + col] = f2bf(v);
            }
        }
    }
}

// ---------------- layer 2: out[sel] = relu(h1 @ W2[:,o,:] + b2[o]) ----------------
__global__ __launch_bounds__(256) void gemm2_kernel(
    const unsigned short* __restrict__ h1, const float* __restrict__ W,
    const float* __restrict__ bias2, const int* __restrict__ sorted_idx,
    const int* __restrict__ offsets, const int* __restrict__ tile_o,
    const int* __restrict__ tile_m, float* __restrict__ out) {
    int o = tile_o[blockIdx.y];
    if (o < 0) return;
    int m0 = tile_m[blockIdx.y];
    int off = offsets[o];
    int cnt = offsets[o + 1] - off;
    int n0 = blockIdx.x * BN;

    __shared__ __attribute__((aligned(16))) unsigned short As[8][BM][8];
    __shared__ __attribute__((aligned(16))) unsigned short Bs[8][BN][8];

    int tid = threadIdx.x;

    int arow = tid & 31, ag = tid >> 5;
    int rr = m0 + arow; if (rr >= cnt) rr = cnt - 1;
    const unsigned short* aBase = h1 + (size_t)(off + rr) * Hn;

    int o8 = tid >> 5, c4 = (tid & 31) * 4;
    const float* bBase = W + ((size_t)(o8 * 8) * On + o) * Hn + n0 + c4;

    short8v a_pre;
    float4v b_pre[8];

    auto LOADA = [&](int kt) {
        a_pre = *(const short8v*)(aBase + kt + ag * 8);
    };
    auto LOADB = [&](int kt) {
        const float* p = bBase + (size_t)kt * OHn;
#pragma unroll
        for (int j = 0; j < 8; ++j) b_pre[j] = *(const float4v*)(p + (size_t)j * OHn);
    };
    auto WRITE = [&]() {
        *(short8v*)&As[ag][arow][0] = a_pre;
#pragma unroll
        for (int cc = 0; cc < 4; ++cc) {
            short8v w;
#pragma unroll
            for (int j = 0; j < 8; ++j) w[j] = (short)f2bf(b_pre[j][cc]);
            *(short8v*)&Bs[o8][swz(c4 + cc)][0] = w;
        }
    };

    floatx4 acc[4] = {};
    int lane = tid & 63, wave = tid >> 6;
    int wm = (wave >> 1) * 16, wn = (wave & 1) * 64;
    int l15 = lane & 15, kg = lane >> 4;

    auto COMPUTE = [&]() {
#pragma unroll
        for (int ks = 0; ks < 2; ++ks) {
            int g = ks * 4 + kg;
            bf16x8 af = *(const bf16x8*)&As[g][wm + l15][0];
            bf16x8 bfr[4];
#pragma unroll
            for (int nt = 0; nt < 4; ++nt) bfr[nt] = *(const bf16x8*)&Bs[g][swz(wn + nt * 16 + l15)][0];
#pragma unroll
            for (int nt = 0; nt < 4; ++nt)
                acc[nt] = __builtin_amdgcn_mfma_f32_16x16x32_bf16(af, bfr[nt], acc[nt], 0, 0, 0);
        }
    };

    LOADA(0); LOADB(0);
    for (int kt = 0; kt < Hn; kt += BK) {
        WRITE();
        __syncthreads();
        int ktn = kt + BK;
        if (ktn < Hn) { LOADA(ktn); LOADB(ktn); }
        COMPUTE();
        __syncthreads();
    }

    // epilogue: bias + relu, scatter rows back to original order (fp32)
    int r4 = (lane >> 4) * 4;
    float bv[4];
#pragma unroll
    for (int nt = 0; nt < 4; ++nt) bv[nt] = bias2[o * Hn + n0 + wn + nt * 16 + l15];
#pragma unroll
    for (int r = 0; r < 4; ++r) {
        int row = m0 + wm + r4 + r;
        if (row < cnt) {
            int b = sorted_idx[off + row];
            float* orow = out + (size_t)b * Hn + n0 + wn + l15;
#pragma unroll
            for (int nt = 0; nt < 4; ++nt) {
                float v = acc[nt][r] + bv[nt];
                orow[nt * 16] = v > 0.f ? v : 0.f;
            }
        }
    }
}

extern "C" void kernel_launch(void* const* d_in, const int* in_sizes, int n_in,
                              void* d_out, int out_size, void* d_ws, size_t ws_size,
                              hipStream_t stream) {
    const float* x      = (const float*)d_in[0];
    const int*   op_idx = (const int*)d_in[1];
    const float* W1     = (const float*)d_in[2];
    const float* bias1  = (const float*)d_in[3];
    const float* W2     = (const float*)d_in[4];
    const float* bias2  = (const float*)d_in[5];
    float* out = (float*)d_out;

    char* ws = (char*)d_ws;
    int* offsets    = (int*)ws;                  // 17 ints
    int* sorted_idx = (int*)(ws + 256);          // 4096 ints
    int* tile_o     = (int*)(ws + 17408);        // MAXT ints (640 B)
    int* tile_m     = (int*)(ws + 18432);        // MAXT ints (640 B)

    const size_t HDR = 32768;
    unsigned short* x_s = (unsigned short*)(ws + HDR);            // 8 MB bf16
    unsigned short* h1  = x_s + (size_t)Bn * En;                  // 8 MB bf16

    hipLaunchKernelGGL(bucket_kernel, dim3(1), dim3(1024), 0, stream,
                       op_idx, sorted_idx, offsets, tile_o, tile_m);
    hipLaunchKernelGGL(pack_x_kernel, dim3(Bn / 4), dim3(256), 0, stream,
                       x, sorted_idx, x_s);
    hipLaunchKernelGGL(gemm1_kernel, dim3(Hn / BN, MAXT), dim3(256), 0, stream,
                       x_s, W1, bias1, offsets, tile_o, tile_m, h1);
    hipLaunchKernelGGL(gemm2_kernel, dim3(Hn / BN, MAXT), dim3(256), 0, stream,
                       h1, W2, bias2, sorted_idx, offsets, tile_o, tile_m, out);
}

// Round 10
// 233.161 us; speedup vs baseline: 1.1591x; 1.1591x over previous
//
#include <hip/hip_runtime.h>

#define Bn 4096
#define En 1024
#define On 16
#define Hn 1024
#define OHn (On * Hn)

#define BM 64
#define BN 128
#define BK 64
#define KSTEPS 16  // En/BK == Hn/BK
#define MAXT 80    // max tiles: sum ceil(cnt/64) <= 64 + 16

using floatx4 = __attribute__((ext_vector_type(4))) float;
using float4v = __attribute__((ext_vector_type(4))) float;
using bf16x8  = __attribute__((ext_vector_type(8))) __bf16;
using short8v = __attribute__((ext_vector_type(8))) short;
using short4v = __attribute__((ext_vector_type(4))) short;

__device__ inline unsigned short f2bf(float f) {
    unsigned u = __builtin_bit_cast(unsigned, f);
    u += 0x7fffu + ((u >> 16) & 1u);   // RNE to bf16 (inputs finite)
    return (unsigned short)(u >> 16);
}

// LDS column swizzle: XOR bits[1:0] of the 16B-cell index with bits[4:3].
// Bijective; spreads k-octet-major B writes and fragment reads across banks
// with compile-time vector indices only (rule #20).
__device__ __forceinline__ int swz(int col) { return col ^ ((col >> 3) & 3); }

// ---------------- bucket examples by op + build compact tile list ----------------
__global__ void bucket_kernel(const int* __restrict__ op_idx,
                              int* __restrict__ sorted_idx,
                              int* __restrict__ offsets,
                              int* __restrict__ tile_o,
                              int* __restrict__ tile_m) {
    __shared__ int cnt[On], cur[On], off[On + 1];
    int tid = threadIdx.x;
    if (tid < On) { cnt[tid] = 0; cur[tid] = 0; }
    __syncthreads();
    for (int i = tid; i < Bn; i += blockDim.x) atomicAdd(&cnt[op_idx[i]], 1);
    __syncthreads();
    if (tid == 0) {
        int s = 0;
        for (int o = 0; o < On; ++o) { off[o] = s; s += cnt[o]; }
        off[On] = s;
        int nt = 0;
        for (int o = 0; o < On; ++o)
            for (int m0 = 0; m0 < cnt[o]; m0 += BM) { tile_o[nt] = o; tile_m[nt] = m0; ++nt; }
        for (; nt < MAXT; ++nt) { tile_o[nt] = -1; tile_m[nt] = 0; }
    }
    __syncthreads();
    for (int i = tid; i < Bn; i += blockDim.x) {
        int o = op_idx[i];
        int p = off[o] + atomicAdd(&cur[o], 1);
        sorted_idx[p] = i;
    }
    if (tid <= On) offsets[tid] = off[tid];
}

// ---------------- pack x: gather rows into sorted order, fp32 -> bf16 ----------------
__global__ __launch_bounds__(256) void pack_x_kernel(const float* __restrict__ x,
                                                     const int* __restrict__ sorted_idx,
                                                     unsigned short* __restrict__ x_s) {
    int p0 = blockIdx.x * 4, t = threadIdx.x;
#pragma unroll
    for (int r = 0; r < 4; ++r) {
        int p = p0 + r;
        int row = sorted_idx[p];
        float4v v = *(const float4v*)(x + (size_t)row * En + t * 4);
        short4v w;
#pragma unroll
        for (int j = 0; j < 4; ++j) w[j] = (short)f2bf(v[j]);
        *(short4v*)&x_s[(size_t)p * En + t * 4] = w;
    }
}

// ================================================================================
// Direct-W GEMM (round-8 structure, BM=64) + DEPTH-2 register prefetch:
// two staging slots; loads for tile i+2 issue at step i -> issue-to-use distance
// ~2 K-steps (vs 1), covering loaded-HBM latency. Compiler emits counted vmcnt
// per register slot automatically. All slot indices compile-time via full unroll.
// ================================================================================

// ---------------- layer 1: h1 = relu(x_s @ W1[:,o,:] + b1[o]) ----------------
__global__ __launch_bounds__(256) void gemm1_kernel(
    const unsigned short* __restrict__ x_s, const float* __restrict__ W,
    const float* __restrict__ bias1, const int* __restrict__ offsets,
    const int* __restrict__ tile_o, const int* __restrict__ tile_m,
    unsigned short* __restrict__ h1) {
    int o = tile_o[blockIdx.y];
    if (o < 0) return;
    int m0 = tile_m[blockIdx.y];
    int off = offsets[o];
    int cnt = offsets[o + 1] - off;
    int n0 = blockIdx.x * BN;

    __shared__ __attribute__((aligned(16))) unsigned short As[8][BM][8];  // 8 KB
    __shared__ __attribute__((aligned(16))) unsigned short Bs[8][BN][8];  // 16 KB

    int tid = threadIdx.x;

    // A: thread owns granule cells (ag, arow), (ag+4, arow)
    int arow = tid & 63, ag = tid >> 6;
    int rr = m0 + arow; if (rr >= cnt) rr = cnt - 1;   // clamp: pad rows never stored
    const unsigned short* aBase = x_s + (size_t)(off + rr) * En;

    // B: thread owns k-octet o8 = tid>>5 (rows o8*8..+7), cols c4..c4+3
    int o8 = tid >> 5, c4 = (tid & 31) * 4;
    const float* bBase = W + ((size_t)(o8 * 8) * On + o) * Hn + n0 + c4;

    short8v a_pre[2][2];
    float4v b_pre[2][8];

    auto LOADA = [&](int sl, int kt) {
        a_pre[sl][0] = *(const short8v*)(aBase + kt + ag * 8);
        a_pre[sl][1] = *(const short8v*)(aBase + kt + (ag + 4) * 8);
    };
    auto LOADB = [&](int sl, int kt) {  // 8 x float4; wave = 2 contiguous 512B rows/instr
        const float* p = bBase + (size_t)kt * OHn;
#pragma unroll
        for (int j = 0; j < 8; ++j) b_pre[sl][j] = *(const float4v*)(p + (size_t)j * OHn);
    };
    auto WRITE = [&](int sl) {
        *(short8v*)&As[ag][arow][0]     = a_pre[sl][0];
        *(short8v*)&As[ag + 4][arow][0] = a_pre[sl][1];
#pragma unroll
        for (int cc = 0; cc < 4; ++cc) {            // cc compile-time: b_pre stays in VGPRs
            short8v w;
#pragma unroll
            for (int j = 0; j < 8; ++j) w[j] = (short)f2bf(b_pre[sl][j][cc]);
            *(short8v*)&Bs[o8][swz(c4 + cc)][0] = w;
        }
    };

    floatx4 acc[2][4] = {};
    int lane = tid & 63, wave = tid >> 6;
    int wm = (wave >> 1) * 32, wn = (wave & 1) * 64;
    int l15 = lane & 15, kg = lane >> 4;

    auto COMPUTE = [&]() {
#pragma unroll
        for (int ks = 0; ks < 2; ++ks) {
            int g = ks * 4 + kg;
            bf16x8 af[2], bfr[4];
#pragma unroll
            for (int mt = 0; mt < 2; ++mt) af[mt] = *(const bf16x8*)&As[g][wm + mt * 16 + l15][0];
#pragma unroll
            for (int nt = 0; nt < 4; ++nt) bfr[nt] = *(const bf16x8*)&Bs[g][swz(wn + nt * 16 + l15)][0];
#pragma unroll
            for (int mt = 0; mt < 2; ++mt)
#pragma unroll
                for (int nt = 0; nt < 4; ++nt)
                    acc[mt][nt] = __builtin_amdgcn_mfma_f32_16x16x32_bf16(af[mt], bfr[nt], acc[mt][nt], 0, 0, 0);
        }
    };

    // depth-2 pipeline: slots hold tiles i and i+1; step i refills slot (i&1) with i+2
    LOADA(0, 0);      LOADB(0, 0);
    LOADA(1, BK);     LOADB(1, BK);
#pragma unroll
    for (int i = 0; i < KSTEPS; ++i) {
        const int sl = i & 1;                       // compile-time after unroll
        WRITE(sl);                                  // waits only slot sl's loads (vmcnt(10))
        __syncthreads();                            // LDS visible
        int ktn = (i + 2) * BK;
        if (ktn < En) { LOADA(sl, ktn); LOADB(sl, ktn); }  // 2-step-ahead prefetch
        COMPUTE();
        __syncthreads();                            // all reads done before next WRITE
    }

    // epilogue: bias + relu -> h1 (bf16, sorted order)
    int r4 = (lane >> 4) * 4;
#pragma unroll
    for (int nt = 0; nt < 4; ++nt) {
        int col = n0 + wn + nt * 16 + l15;
        float bv = bias1[o * Hn + col];
#pragma unroll
        for (int mt = 0; mt < 2; ++mt) {
#pragma unroll
            for (int r = 0; r < 4; ++r) {
                int row = m0 + wm + mt * 16 + r4 + r;
                if (row < cnt) {
                    float v = acc[mt][nt][r] + bv;
                    v = v > 0.f ? v : 0.f;
                    h1[(size_t)(off + row) * Hn + col] = f2bf(v);
                }
            }
        }
    }
}

// ---------------- layer 2: out[sel] = relu(h1 @ W2[:,o,:] + b2[o]) ----------------
__global__ __launch_bounds__(256) void gemm2_kernel(
    const unsigned short* __restrict__ h1, const float* __restrict__ W,
    const float* __restrict__ bias2, const int* __restrict__ sorted_idx,
    const int* __restrict__ offsets, const int* __restrict__ tile_o,
    const int* __restrict__ tile_m, float* __restrict__ out) {
    int o = tile_o[blockIdx.y];
    if (o < 0) return;
    int m0 = tile_m[blockIdx.y];
    int off = offsets[o];
    int cnt = offsets[o + 1] - off;
    int n0 = blockIdx.x * BN;

    __shared__ __attribute__((aligned(16))) unsigned short As[8][BM][8];
    __shared__ __attribute__((aligned(16))) unsigned short Bs[8][BN][8];

    int tid = threadIdx.x;

    int arow = tid & 63, ag = tid >> 6;
    int rr = m0 + arow; if (rr >= cnt) rr = cnt - 1;
    const unsigned short* aBase = h1 + (size_t)(off + rr) * Hn;

    int o8 = tid >> 5, c4 = (tid & 31) * 4;
    const float* bBase = W + ((size_t)(o8 * 8) * On + o) * Hn + n0 + c4;

    short8v a_pre[2][2];
    float4v b_pre[2][8];

    auto LOADA = [&](int sl, int kt) {
        a_pre[sl][0] = *(const short8v*)(aBase + kt + ag * 8);
        a_pre[sl][1] = *(const short8v*)(aBase + kt + (ag + 4) * 8);
    };
    auto LOADB = [&](int sl, int kt) {
        const float* p = bBase + (size_t)kt * OHn;
#pragma unroll
        for (int j = 0; j < 8; ++j) b_pre[sl][j] = *(const float4v*)(p + (size_t)j * OHn);
    };
    auto WRITE = [&](int sl) {
        *(short8v*)&As[ag][arow][0]     = a_pre[sl][0];
        *(short8v*)&As[ag + 4][arow][0] = a_pre[sl][1];
#pragma unroll
        for (int cc = 0; cc < 4; ++cc) {
            short8v w;
#pragma unroll
            for (int j = 0; j < 8; ++j) w[j] = (short)f2bf(b_pre[sl][j][cc]);
            *(short8v*)&Bs[o8][swz(c4 + cc)][0] = w;
        }
    };

    floatx4 acc[2][4] = {};
    int lane = tid & 63, wave = tid >> 6;
    int wm = (wave >> 1) * 32, wn = (wave & 1) * 64;
    int l15 = lane & 15, kg = lane >> 4;

    auto COMPUTE = [&]() {
#pragma unroll
        for (int ks = 0; ks < 2; ++ks) {
            int g = ks * 4 + kg;
            bf16x8 af[2], bfr[4];
#pragma unroll
            for (int mt = 0; mt < 2; ++mt) af[mt] = *(const bf16x8*)&As[g][wm + mt * 16 + l15][0];
#pragma unroll
            for (int nt = 0; nt < 4; ++nt) bfr[nt] = *(const bf16x8*)&Bs[g][swz(wn + nt * 16 + l15)][0];
#pragma unroll
            for (int mt = 0; mt < 2; ++mt)
#pragma unroll
                for (int nt = 0; nt < 4; ++nt)
                    acc[mt][nt] = __builtin_amdgcn_mfma_f32_16x16x32_bf16(af[mt], bfr[nt], acc[mt][nt], 0, 0, 0);
        }
    };

    LOADA(0, 0);      LOADB(0, 0);
    LOADA(1, BK);     LOADB(1, BK);
#pragma unroll
    for (int i = 0; i < KSTEPS; ++i) {
        const int sl = i & 1;
        WRITE(sl);
        __syncthreads();
        int ktn = (i + 2) * BK;
        if (ktn < Hn) { LOADA(sl, ktn); LOADB(sl, ktn); }
        COMPUTE();
        __syncthreads();
    }

    // epilogue: bias + relu, scatter rows back to original order (fp32)
    int r4 = (lane >> 4) * 4;
    float bv[4];
#pragma unroll
    for (int nt = 0; nt < 4; ++nt) bv[nt] = bias2[o * Hn + n0 + wn + nt * 16 + l15];
#pragma unroll
    for (int mt = 0; mt < 2; ++mt) {
#pragma unroll
        for (int r = 0; r < 4; ++r) {
            int row = m0 + wm + mt * 16 + r4 + r;
            if (row < cnt) {
                int b = sorted_idx[off + row];
                float* orow = out + (size_t)b * Hn + n0 + wn + l15;
#pragma unroll
                for (int nt = 0; nt < 4; ++nt) {
                    float v = acc[mt][nt][r] + bv[nt];
                    orow[nt * 16] = v > 0.f ? v : 0.f;
                }
            }
        }
    }
}

extern "C" void kernel_launch(void* const* d_in, const int* in_sizes, int n_in,
                              void* d_out, int out_size, void* d_ws, size_t ws_size,
                              hipStream_t stream) {
    const float* x      = (const float*)d_in[0];
    const int*   op_idx = (const int*)d_in[1];
    const float* W1     = (const float*)d_in[2];
    const float* bias1  = (const float*)d_in[3];
    const float* W2     = (const float*)d_in[4];
    const float* bias2  = (const float*)d_in[5];
    float* out = (float*)d_out;

    char* ws = (char*)d_ws;
    int* offsets    = (int*)ws;                  // 17 ints
    int* sorted_idx = (int*)(ws + 256);          // 4096 ints
    int* tile_o     = (int*)(ws + 17408);        // MAXT ints
    int* tile_m     = (int*)(ws + 18432);        // MAXT ints

    const size_t HDR = 32768;
    unsigned short* x_s = (unsigned short*)(ws + HDR);            // 8 MB bf16
    unsigned short* h1  = x_s + (size_t)Bn * En;                  // 8 MB bf16

    hipLaunchKernelGGL(bucket_kernel, dim3(1), dim3(1024), 0, stream,
                       op_idx, sorted_idx, offsets, tile_o, tile_m);
    hipLaunchKernelGGL(pack_x_kernel, dim3(Bn / 4), dim3(256), 0, stream,
                       x, sorted_idx, x_s);
    hipLaunchKernelGGL(gemm1_kernel, dim3(Hn / BN, MAXT), dim3(256), 0, stream,
                       x_s, W1, bias1, offsets, tile_o, tile_m, h1);
    hipLaunchKernelGGL(gemm2_kernel, dim3(Hn / BN, MAXT), dim3(256), 0, stream,
                       h1, W2, bias2, sorted_idx, offsets, tile_o, tile_m, out);
}